// Round 10
// baseline (163.729 us; speedup 1.0000x reference)
//
#include <hip/hip_runtime.h>
#include <hip/hip_bf16.h>

#define NROWS 8192
#define DIM   512
#define KSEL  20
#define PANEL 1024
#define NSURV 512

typedef unsigned int u32;
typedef unsigned long long u64;
typedef short bf16x8 __attribute__((ext_vector_type(8)));
typedef float f32x4 __attribute__((ext_vector_type(4)));
typedef ushort u16x2 __attribute__((ext_vector_type(2)));

typedef const void __attribute__((address_space(1))) as1_void;
typedef void __attribute__((address_space(3))) as3_void;

__device__ __forceinline__ void async_ld16(const ushort* g, ushort* l) {
    __builtin_amdgcn_global_load_lds((as1_void*)g, (as3_void*)l, 16, 0, 0);
}

// round-to-nearest-even f32 -> bf16 bits
__device__ __forceinline__ ushort f2bf(float f) {
    u32 u = __float_as_uint(f);
    return (ushort)((u + 0x7FFFu + ((u >> 16) & 1u)) >> 16);
}

// monotone map for one u16 bf16 pattern: integer compare == float compare
__device__ __forceinline__ u32 mono16(u32 r) {
    return r ^ (0x8000u | ((r >> 15) * 0x7FFFu));
}

__device__ __forceinline__ u32 mkey(float f) { return mono16((u32)f2bf(f)); }

// packed u16x2 max
__device__ __forceinline__ u32 pkmax(u32 a, u32 b) {
    union { u32 u; u16x2 v; } x, y; x.u = a; y.u = b;
    x.v = __builtin_elementwise_max(x.v, y.v);
    return x.u;
}

// ---------------- normalize: fp32 rows -> unit-norm bf16, K-panel-major ------
// xn layout: [DIM/32 panels][NROWS][32] ushort. A 128-row x 32-col GEMM
// staging tile is CONTIGUOUS 8KB -> every global_load_lds wave reads full
// 128B lines (r6-r9's [row][DIM] layout at BK=32 read half-lines: FETCH
// 99 -> 123MB). Write side here: 16 x 64B scatter per row, xn is 8MB total.
__global__ __launch_bounds__(256) void k_norm(const float* __restrict__ x,
                                              ushort* __restrict__ xn) {
    int lane = threadIdx.x & 63;
    int wv   = threadIdx.x >> 6;
    int row  = blockIdx.x * 4 + wv;
    const float4* xr = (const float4*)(x + (size_t)row * DIM);
    float4 a = xr[2 * lane];
    float4 b = xr[2 * lane + 1];
    float ss = a.x*a.x + a.y*a.y + a.z*a.z + a.w*a.w
             + b.x*b.x + b.y*b.y + b.z*b.z + b.w*b.w;
    #pragma unroll
    for (int off = 32; off; off >>= 1) ss += __shfl_xor(ss, off);
    float sc = 1.0f / fmaxf(sqrtf(ss), 1e-12f);
    float v[8] = {a.x*sc, a.y*sc, a.z*sc, a.w*sc, b.x*sc, b.y*sc, b.z*sc, b.w*sc};
    union { ushort u[8]; uint4 q; } o;
    #pragma unroll
    for (int i = 0; i < 8; ++i) o.u[i] = f2bf(v[i]);
    // panel = lane>>2 (8 elems = 1/4 of a 32-col panel), chunk-in-panel = lane&3
    *(uint4*)(xn + (size_t)(lane >> 2) * (NROWS * 32)
                 + (size_t)row * 32 + (lane & 3) * 8) = o.q;
}

// ---------------- GEMM: C = Xn * Xn^T (bf16 out), diag = -3.0 ----------------
// 128x128 tile, 4 waves (2x2), each wave 4x4 subtiles of 16x16x32 bf16 MFMA.
// BK=32 double-buffered counted-vmcnt pipeline (r6-proven), K-panel-major xn:
//   each STAGE wave-instruction reads 1KB CONTIGUOUS (8 full lines). LDS
//   dest + XOR pre-swizzle identical to r6 (verified): lane chunk
//   sch=(l&3)^((srow>>1)&3); compute reads chunk q^((row>>1)&3).
//   __launch_bounds__(256,4) -> VGPR 64, 4 blocks/CU. Per step: issue next
//   tile's loads FIRST, vmcnt(4) (waits only PREVIOUS tile), s_barrier,
//   ds_read+16 MFMA, s_barrier. Never vmcnt(0) in-loop.
// Epilogue: LDS-staged coalesced b128 TEMPORAL stores (NT proven no-op r9;
// temporal keeps C L3-resident for k_select); transposed seg-major M digest.
template<bool TRI>
__global__ __launch_bounds__(256, 4) void k_gemm(const ushort* __restrict__ xn,
                                                 ushort* __restrict__ C,
                                                 ushort* __restrict__ M,
                                                 int row0) {
    __shared__ ushort sh[128 * 128];         // K-loop: A0|A1|B0|B1; epi: tile
    int tid  = threadIdx.x;
    int lane = tid & 63, wv = tid >> 6;
    int wr = wv >> 1, wc = wv & 1;
    int q = lane >> 4, m = lane & 15;
    int bx, by;
    if (TRI) {
        int t = (int)blockIdx.x;
        t = (t & 7) * 260 + (t >> 3);        // XCD swizzle: 2080 = 8*260 (bijective)
        by = (int)((sqrtf(8.0f * (float)t + 1.0f) - 1.0f) * 0.5f);
        while ((by + 1) * (by + 2) / 2 <= t) ++by;
        while (by * (by + 1) / 2 > t) --by;
        bx = t - by * (by + 1) / 2;          // bx <= by
    } else {
        bx = blockIdx.x; by = blockIdx.y;
    }
    int grow0 = row0 + by * 128;   // A rows (global)
    int gcol0 = bx * 128;          // B rows = C cols (global)
    f32x4 acc[4][4] = {};

    // LDS regions (ushort offsets): A(buf)=buf*4096, B(buf)=8192+buf*4096
    int srow = lane >> 2;                    // row within 16-row staging group
    int sch  = (lane & 3) ^ ((srow >> 1) & 3); // pre-swizzled source chunk
    // stage K-panel kc into buffer buf: 4 global_load_lds per thread;
    // xn panel-major: tile rows are contiguous -> full-line reads
    #define STAGE(buf, kc)                                                          \
        _Pragma("unroll")                                                           \
        for (int t_ = 0; t_ < 2; ++t_) {                                            \
            int rb_ = wv * 32 + t_ * 16;                                            \
            const ushort* ga_ = xn + (size_t)(kc) * (NROWS * 32)                    \
                                   + (size_t)(grow0 + rb_ + srow) * 32 + sch * 8;   \
            const ushort* gb_ = xn + (size_t)(kc) * (NROWS * 32)                    \
                                   + (size_t)(gcol0 + rb_ + srow) * 32 + sch * 8;   \
            async_ld16(ga_, &sh[(buf) * 4096 + rb_ * 32]);                          \
            async_ld16(gb_, &sh[8192 + (buf) * 4096 + rb_ * 32]);                   \
        }

    STAGE(0, 0);
    for (int kc = 0; kc < 16; ++kc) {
        int cur = kc & 1;
        if (kc < 15) {
            STAGE(cur ^ 1, kc + 1);
            asm volatile("s_waitcnt vmcnt(4)" ::: "memory");
        } else {
            asm volatile("s_waitcnt vmcnt(0)" ::: "memory");
        }
        __builtin_amdgcn_s_barrier();        // current tile staged (all waves)
        __builtin_amdgcn_sched_barrier(0);
        {
            const ushort* A = sh + cur * 4096;
            const ushort* B = sh + 8192 + cur * 4096;
            bf16x8 af[4], bfr[4];
            #pragma unroll
            for (int i = 0; i < 4; ++i) {
                int ra  = wr * 64 + i * 16 + m;
                int rb2 = wc * 64 + i * 16 + m;
                af[i]  = *(const bf16x8*)&A[ra  * 32 + ((q ^ ((ra  >> 1) & 3)) * 8)];
                bfr[i] = *(const bf16x8*)&B[rb2 * 32 + ((q ^ ((rb2 >> 1) & 3)) * 8)];
            }
            #pragma unroll
            for (int i = 0; i < 4; ++i)
                #pragma unroll
                for (int j = 0; j < 4; ++j)
                    acc[i][j] = __builtin_amdgcn_mfma_f32_16x16x32_bf16(af[i], bfr[j], acc[i][j], 0, 0, 0);
        }
        __builtin_amdgcn_sched_barrier(0);
        __builtin_amdgcn_s_barrier();        // buffer reusable next iteration
    }
    #undef STAGE

    // ---- epilogue phase 1: stage row-tile in LDS + M digest ----
    // C/D layout: col=lane&15, row=quad*4+reg (m89/m91-verified)
    float cmf[4] = {-3.0f, -3.0f, -3.0f, -3.0f};     // per-j col maxima
    #pragma unroll
    for (int i = 0; i < 4; ++i) {
        float rmf[4] = {-3.0f, -3.0f, -3.0f, -3.0f}; // per-reg row maxima
        int rloc = wr * 64 + i * 16 + q * 4;         // local row base (0..127)
        #pragma unroll
        for (int j = 0; j < 4; ++j) {
            int cl = wc * 64 + j * 16 + m;           // local col
            int c  = gcol0 + cl;                     // global col
            #pragma unroll
            for (int reg = 0; reg < 4; ++reg) {
                int r    = rloc + reg;
                int grw  = row0 + by * 128 + r;
                float a  = acc[i][j][reg];
                bool dg  = (grw == c);
                float mv = dg ? -3.0f : a;
                rmf[reg] = fmaxf(rmf[reg], mv);
                cmf[j]   = fmaxf(cmf[j], mv);
                // dword-swizzled row-tile write (conflict-free; q=(r>>2)&3)
                int D = r * 64 + ((cl >> 1) ^ (q << 3));
                sh[D * 2 + (cl & 1)] = dg ? (ushort)0xC040 : f2bf(a);
            }
        }
        // row maxima: packed 2-rows/u32, reduce over 16 lanes (m) of each quad
        u32 p01 = mkey(rmf[0]) | (mkey(rmf[1]) << 16);
        u32 p23 = mkey(rmf[2]) | (mkey(rmf[3]) << 16);
        #pragma unroll
        for (int off = 1; off <= 8; off <<= 1) {
            p01 = pkmax(p01, (u32)__shfl_xor((int)p01, off));
            p23 = pkmax(p23, (u32)__shfl_xor((int)p23, off));
        }
        if (m == 0) {
            // transposed M: seg-major, rows rloc..rloc+3 contiguous -> one u64
            u64 pk = (u64)p01 | ((u64)p23 << 32);
            *(u64*)&M[(size_t)(bx * 2 + wc) * NROWS + (row0 + by * 128 + rloc)] = pk;
        }
    }
    if (TRI && bx != by) {
        // col maxima (mirror rows): packed 2-cols/u32, reduce over quads (q)
        u32 q01 = mkey(cmf[0]) | (mkey(cmf[1]) << 16);
        u32 q23 = mkey(cmf[2]) | (mkey(cmf[3]) << 16);
        q01 = pkmax(q01, (u32)__shfl_xor((int)q01, 16));
        q01 = pkmax(q01, (u32)__shfl_xor((int)q01, 32));
        q23 = pkmax(q23, (u32)__shfl_xor((int)q23, 16));
        q23 = pkmax(q23, (u32)__shfl_xor((int)q23, 32));
        if (q == 0) {
            // transposed M: 16 m-lanes write 16 contiguous ushorts per group
            int gc = gcol0 + wc * 64 + m;
            size_t sb = (size_t)(by * 2 + wr) * NROWS + gc;
            M[sb +  0] = (ushort)(q01 & 0xFFFFu);
            M[sb + 16] = (ushort)(q01 >> 16);
            M[sb + 32] = (ushort)(q23 & 0xFFFFu);
            M[sb + 48] = (ushort)(q23 >> 16);
        }
    }
    __syncthreads();

    // ---- epilogue phase 2a: coalesced row-major readback & store ----
    int tr = tid >> 4;       // 0..15
    int tc = tid & 15;       // 8-col chunk
    #pragma unroll
    for (int p = 0; p < 8; ++p) {
        int r  = p * 16 + tr;
        int qr = (r >> 2) & 3;
        uint4 v = *(const uint4*)&sh[(r * 64 + ((tc * 4) ^ (qr << 3))) * 2];
        *(uint4*)&C[(size_t)(by * 128 + r) * NROWS + gcol0 + tc * 8] = v;
    }

    if (TRI && bx != by) {
        // ---- phase 2b: re-stage transposed tile (packed row-pair b32) ----
        __syncthreads();
        u32* sh32 = (u32*)sh;
        #pragma unroll
        for (int i = 0; i < 4; ++i) {
            int cd0 = wr * 32 + i * 8 + q * 2;       // C^T dword col (rows rloc..+1)
            #pragma unroll
            for (int j = 0; j < 4; ++j) {
                int rT = wc * 64 + j * 16 + m;       // C^T row = orig col
                int gT = ((rT >> 2) & 3) << 3;
                u32 w0 = (u32)f2bf(acc[i][j][0]) | ((u32)f2bf(acc[i][j][1]) << 16);
                u32 w1 = (u32)f2bf(acc[i][j][2]) | ((u32)f2bf(acc[i][j][3]) << 16);
                sh32[rT * 64 + (cd0 ^ gT)]       = w0;
                sh32[rT * 64 + ((cd0 + 1) ^ gT)] = w1;
            }
        }
        __syncthreads();
        // ---- phase 2c: coalesced transposed readback & store ----
        #pragma unroll
        for (int p = 0; p < 8; ++p) {
            int ct = p * 16 + tr;                    // mirror global row gcol0+ct
            int gq = ((ct >> 2) & 3) << 3;
            uint4 v = *(const uint4*)&sh32[ct * 64 + ((tc * 4) ^ gq)];
            *(uint4*)&C[(size_t)(gcol0 + ct) * NROWS + by * 128 + tc * 8] = v;
        }
    }
}

// ---------------- select: ballot-bsearch top-20 + BCE ------------------------
__global__ __launch_bounds__(256) void k_select(const ushort* __restrict__ C,
                                                const ushort* __restrict__ M,
                                                const int* __restrict__ labels,
                                                int row0,
                                                float* __restrict__ partials) {
    __shared__ u32 s_surv[4][NSURV];
    __shared__ u32 s_seg[4][128];
    __shared__ u32 s_cnt[4];
    __shared__ u32 s_scnt[4];
    int lane = threadIdx.x & 63;
    int wv   = threadIdx.x >> 6;
    int prow = blockIdx.x * 4 + wv;
    int grow = row0 + prow;
    const ushort* rowC = C + (size_t)prow * NROWS;

    if (lane == 0) { s_cnt[wv] = 0; s_scnt[wv] = 0; }
    __syncthreads();

    // segment maxima (mono keys), transposed M: lane holds segs 2*lane, 2*lane+1
    u32 klo = (u32)M[(size_t)(2 * lane)     * NROWS + grow];
    u32 khi = (u32)M[(size_t)(2 * lane + 1) * NROWS + grow];

    // T = largest 16-bit value with count(seg_max >= T) >= KSEL
    u32 T = 0;
    #pragma unroll
    for (int b = 15; b >= 0; --b) {
        u32 cand = T | (1u << b);
        int c = __popcll(__ballot(klo >= cand)) + __popcll(__ballot(khi >= cand));
        if (c >= KSEL) T = cand;
    }

    // survivor-segment id list in LDS (replaces serial ctz chain)
    if (klo >= T) { u32 p = atomicAdd(&s_scnt[wv], 1u); s_seg[wv][p] = 2u * lane; }
    if (khi >= T) { u32 p = atomicAdd(&s_scnt[wv], 1u); s_seg[wv][p] = 2u * lane + 1u; }
    u32 nseg = s_scnt[wv];
    int grp = lane >> 3, sub = lane & 7;   // 8 lanes per segment

    // fast path: up to 32 segments as 4 independent uint4 loads (one mem epoch)
    int  sid[4];
    uint4 vv[4];
    #pragma unroll
    for (int t = 0; t < 4; ++t) {
        u32 ix = (u32)(t * 8 + grp);
        sid[t] = (ix < nseg) ? (int)s_seg[wv][ix] : -1;
    }
    #pragma unroll
    for (int t = 0; t < 4; ++t) {
        if (sid[t] >= 0) vv[t] = *(const uint4*)(rowC + sid[t] * 64 + sub * 8);
    }
    #pragma unroll
    for (int t = 0; t < 4; ++t) {
        if (sid[t] < 0) continue;
        u32 wds[4] = { vv[t].x, vv[t].y, vv[t].z, vv[t].w };
        u32 cbase = (u32)(sid[t] * 64 + sub * 8);
        #pragma unroll
        for (int h = 0; h < 4; ++h) {
            u32 w  = wds[h];
            u32 kA = mono16(w & 0xFFFFu);
            u32 kB = mono16(w >> 16);
            if (kA >= T) { u32 p = atomicAdd(&s_cnt[wv], 1u); if (p < NSURV) s_surv[wv][p] = (kA << 16) | (cbase + 2u * h); }
            if (kB >= T) { u32 p = atomicAdd(&s_cnt[wv], 1u); if (p < NSURV) s_surv[wv][p] = (kB << 16) | (cbase + 2u * h + 1u); }
        }
    }
    // rare tail: nseg > 32
    for (u32 base = 32; base < nseg; base += 8) {
        u32 ix = base + (u32)grp;
        if (ix >= nseg) continue;
        int s = (int)s_seg[wv][ix];
        uint4 v = *(const uint4*)(rowC + s * 64 + sub * 8);
        u32 wds[4] = { v.x, v.y, v.z, v.w };
        u32 cbase = (u32)(s * 64 + sub * 8);
        #pragma unroll
        for (int h = 0; h < 4; ++h) {
            u32 w  = wds[h];
            u32 kA = mono16(w & 0xFFFFu);
            u32 kB = mono16(w >> 16);
            if (kA >= T) { u32 p = atomicAdd(&s_cnt[wv], 1u); if (p < NSURV) s_surv[wv][p] = (kA << 16) | (cbase + 2u * h); }
            if (kB >= T) { u32 p = atomicAdd(&s_cnt[wv], 1u); if (p < NSURV) s_surv[wv][p] = (kB << 16) | (cbase + 2u * h + 1u); }
        }
    }

    u32 cnt = min(s_cnt[wv], (u32)NSURV);     // same-wave LDS: ordered
    int mylab = labels[grow];
    float loss = 0.0f;

    if (cnt <= 64u) {
        // fast path: one survivor per lane; V20 bsearch = 16 ballots
        u32 gg  = ((u32)lane < cnt) ? s_surv[wv][lane] : 0u;
        u32 key = gg >> 16;
        u32 V = 0;
        #pragma unroll
        for (int b = 15; b >= 0; --b) {
            u32 cand = V | (1u << b);
            if (__popcll(__ballot(key >= cand)) >= KSEL) V = cand;
        }
        int cgt  = __popcll(__ballot(key > V));
        int ceq  = __popcll(__ballot(gg != 0 && key == V));
        int need = KSEL - cgt;
        bool incl;
        if (ceq == need) {
            incl = (gg != 0) && (key >= V);
        } else {
            // more ties than slots: take `need` largest cols among ties
            u32 col = gg & 0xFFFFu;
            bool tie = (gg != 0) && (key == V);
            u32 Cv = 0;
            #pragma unroll
            for (int b = 15; b >= 0; --b) {
                u32 cand2 = Cv | (1u << b);
                if (__popcll(__ballot(tie && col >= cand2)) >= need) Cv = cand2;
            }
            incl = (key > V) || (tie && col >= Cv);   // cols unique -> exact
        }
        if (incl) {
            u32 col = gg & 0xFFFFu;
            u32 raw = (key & 0x8000u) ? (key ^ 0x8000u) : (key ^ 0xFFFFu);
            float v = __uint_as_float(raw << 16);
            float p = (v + 1.0f) * 0.5f;
            bool tm = (labels[col] == mylab);
            loss -= tm ? fmaxf(logf(p), -100.0f) : fmaxf(log1pf(-p), -100.0f);
        }
    } else {
        // fallback (rare): 8 survivors per lane
        u32 g[8];
        #pragma unroll
        for (int j = 0; j < 8; ++j) {
            u32 idx = (u32)lane + (u32)j * 64u;
            g[j] = (idx < cnt) ? s_surv[wv][idx] : 0u;
        }
        u32 V = 0;
        #pragma unroll
        for (int b = 15; b >= 0; --b) {
            u32 cand = V | (1u << b);
            int c = 0;
            #pragma unroll
            for (int j = 0; j < 8; ++j)
                c += __popcll(__ballot((g[j] >> 16) >= cand));
            if (c >= KSEL) V = cand;
        }
        int cgt = 0, ceq = 0;
        #pragma unroll
        for (int j = 0; j < 8; ++j) {
            cgt += __popcll(__ballot(g[j] != 0 && (g[j] >> 16) > V));
            ceq += __popcll(__ballot(g[j] != 0 && (g[j] >> 16) == V));
        }
        int need = KSEL - cgt;
        bool all_ties = (ceq == need);
        #pragma unroll
        for (int j = 0; j < 8; ++j) {
            u32 key = g[j] >> 16, col = g[j] & 0xFFFFu;
            if (g[j] != 0 && (key > V || (all_ties && key == V))) {
                u32 raw = (key & 0x8000u) ? (key ^ 0x8000u) : (key ^ 0xFFFFu);
                float v = __uint_as_float(raw << 16);
                float p = (v + 1.0f) * 0.5f;
                bool tm = (labels[col] == mylab);
                loss -= tm ? fmaxf(logf(p), -100.0f) : fmaxf(log1pf(-p), -100.0f);
            }
        }
        if (!all_ties) {
            for (int r = 0; r < need; ++r) {
                u32 best = 0;
                #pragma unroll
                for (int j = 0; j < 8; ++j) {
                    u32 c2 = (g[j] != 0 && (g[j] >> 16) == V) ? ((g[j] & 0xFFFFu) + 1u) : 0u;
                    best = max(best, c2);
                }
                #pragma unroll
                for (int off = 32; off; off >>= 1) best = max(best, (u32)__shfl_xor((int)best, off));
                #pragma unroll
                for (int j = 0; j < 8; ++j) {
                    if (g[j] != 0 && (g[j] >> 16) == V && ((g[j] & 0xFFFFu) + 1u) == best) {
                        u32 col = g[j] & 0xFFFFu;
                        u32 raw = (V & 0x8000u) ? (V ^ 0x8000u) : (V ^ 0xFFFFu);
                        float v = __uint_as_float(raw << 16);
                        float p = (v + 1.0f) * 0.5f;
                        bool tm = (labels[col] == mylab);
                        loss -= tm ? fmaxf(logf(p), -100.0f) : fmaxf(log1pf(-p), -100.0f);
                        g[j] = 0;
                    }
                }
            }
        }
    }

    #pragma unroll
    for (int off = 32; off; off >>= 1) loss += __shfl_xor(loss, off);
    if (lane == 0) partials[grow] = loss;
}

__global__ __launch_bounds__(256) void k_final(const float* __restrict__ partials,
                                               float* __restrict__ out) {
    __shared__ float s[4];
    int tid = threadIdx.x, lane = tid & 63, wvi = tid >> 6;
    const float4* p4 = (const float4*)partials;
    float sum = 0.0f;
    #pragma unroll
    for (int i = 0; i < 8; ++i) {
        float4 v = p4[tid + i * 256];
        sum += v.x + v.y + v.z + v.w;
    }
    #pragma unroll
    for (int off = 32; off; off >>= 1) sum += __shfl_xor(sum, off);
    if (lane == 0) s[wvi] = sum;
    __syncthreads();
    if (tid == 0) out[0] = (s[0] + s[1] + s[2] + s[3]) * (1.0f / (float)(NROWS * KSEL));
}

extern "C" void kernel_launch(void* const* d_in, const int* in_sizes, int n_in,
                              void* d_out, int out_size, void* d_ws, size_t ws_size,
                              hipStream_t stream) {
    const float* batch  = (const float*)d_in[0];
    const int*   labels = (const int*)d_in[1];

    ushort* xn = (ushort*)d_ws;
    ushort* C  = xn + (size_t)NROWS * DIM;

    size_t xn_b   = (size_t)NROWS * DIM * 2;          //   8 MB
    size_t c_b    = (size_t)NROWS * NROWS * 2;        // 134 MB
    size_t m_b    = (size_t)128 * NROWS * 2;          //   2 MB
    size_t p_b    = (size_t)NROWS * 4;                //  32 KB
    size_t need_full = xn_b + c_b;
    size_t need_all  = need_full + m_b + p_b;

    // M (2 MB, seg-major) + partials in d_ws when headroom allows; else in
    // the batch input buffer (consumed by k_norm first). Both measured-equal.
    ushort* M;
    float*  partials;
    if (ws_size >= need_all) {
        M        = (ushort*)((char*)d_ws + need_full);
        partials = (float*)((char*)d_ws + need_full + m_b);
    } else {
        M        = (ushort*)d_in[0];
        partials = (float*)((char*)d_in[0] + (4u << 20));
    }

    k_norm<<<NROWS / 4, 256, 0, stream>>>(batch, xn);

    if (ws_size >= need_full) {
        // full symmetric path: 2080 lower-triangle blocks, one select pass
        k_gemm<true><<<dim3(64 * 65 / 2), 256, 0, stream>>>(xn, C, M, 0);
        k_select<<<NROWS / 4, 256, 0, stream>>>(C, M, labels, 0, partials);
    } else {
        // fallback: panel path (24 MB of ws)
        for (int p = 0; p < NROWS / PANEL; ++p) {
            k_gemm<false><<<dim3(64, PANEL / 128), 256, 0, stream>>>(xn, C, M, p * PANEL);
            k_select<<<PANEL / 4, 256, 0, stream>>>(C, M, labels, p * PANEL, partials);
        }
    }
    k_final<<<1, 256, 0, stream>>>(partials, (float*)d_out);
}

// Round 11
// 160.108 us; speedup vs baseline: 1.0226x; 1.0226x over previous
//
#include <hip/hip_runtime.h>
#include <hip/hip_bf16.h>

#define NROWS 8192
#define DIM   512
#define KSEL  20
#define PANEL 1024
#define NSURV 512

typedef unsigned int u32;
typedef unsigned long long u64;
typedef short bf16x8 __attribute__((ext_vector_type(8)));
typedef float f32x4 __attribute__((ext_vector_type(4)));
typedef ushort u16x2 __attribute__((ext_vector_type(2)));

typedef const void __attribute__((address_space(1))) as1_void;
typedef void __attribute__((address_space(3))) as3_void;

__device__ __forceinline__ void async_ld16(const ushort* g, ushort* l) {
    __builtin_amdgcn_global_load_lds((as1_void*)g, (as3_void*)l, 16, 0, 0);
}

// round-to-nearest-even f32 -> bf16 bits
__device__ __forceinline__ ushort f2bf(float f) {
    u32 u = __float_as_uint(f);
    return (ushort)((u + 0x7FFFu + ((u >> 16) & 1u)) >> 16);
}

// monotone map for one u16 bf16 pattern: integer compare == float compare
__device__ __forceinline__ u32 mono16(u32 r) {
    return r ^ (0x8000u | ((r >> 15) * 0x7FFFu));
}

__device__ __forceinline__ u32 mkey(float f) { return mono16((u32)f2bf(f)); }

// packed u16x2 max
__device__ __forceinline__ u32 pkmax(u32 a, u32 b) {
    union { u32 u; u16x2 v; } x, y; x.u = a; y.u = b;
    x.v = __builtin_elementwise_max(x.v, y.v);
    return x.u;
}

// ---------------- normalize: fp32 rows -> unit-norm bf16 rows ----------------
__global__ __launch_bounds__(256) void k_norm(const float* __restrict__ x,
                                              ushort* __restrict__ xn) {
    int lane = threadIdx.x & 63;
    int wv   = threadIdx.x >> 6;
    int row  = blockIdx.x * 4 + wv;
    const float4* xr = (const float4*)(x + (size_t)row * DIM);
    float4 a = xr[2 * lane];
    float4 b = xr[2 * lane + 1];
    float ss = a.x*a.x + a.y*a.y + a.z*a.z + a.w*a.w
             + b.x*b.x + b.y*b.y + b.z*b.z + b.w*b.w;
    #pragma unroll
    for (int off = 32; off; off >>= 1) ss += __shfl_xor(ss, off);
    float sc = 1.0f / fmaxf(sqrtf(ss), 1e-12f);
    float v[8] = {a.x*sc, a.y*sc, a.z*sc, a.w*sc, b.x*sc, b.y*sc, b.z*sc, b.w*sc};
    union { ushort u[8]; uint4 q; } o;
    #pragma unroll
    for (int i = 0; i < 8; ++i) o.u[i] = f2bf(v[i]);
    *(uint4*)(xn + (size_t)row * DIM + lane * 8) = o.q;
}

// ---------------- GEMM: C = Xn * Xn^T (bf16 out), diag = -3.0 ----------------
// 128x128 tile, 4 waves (2x2), each wave 4x4 subtiles of 16x16x32 bf16 MFMA.
// r4 configuration — BEST TIMED (158.3us): BK=64 2-barrier K-loop, 4 blk/CU,
// XCD-bijective triangle swizzle, block-private full-line seg-major M digest,
// LDS-staged coalesced b128 epilogue for both tiles.
// LEDGER (r5-r10): counted-vmcnt BK=32 pipeline improved isolated replay
// (105->85us) but ALWAYS regressed the timed metric (158->162-165) — it adds
// ~100MB of HBM traffic (FETCH 90->123 from deeper prefetch working set;
// WRITE 133->198 occupancy-correlated write-amp that survived NT/layout/
// placement fixes). Timed window is traffic-bound, not latency-bound.
template<bool TRI>
__global__ __launch_bounds__(256) void k_gemm(const ushort* __restrict__ xn,
                                              ushort* __restrict__ C,
                                              ushort* __restrict__ M,
                                              int row0) {
    __shared__ ushort sh[128 * 128];         // K-loop: A|B staging; epi: tile
    ushort* lA = sh;
    ushort* lB = sh + 128 * 64;
    int tid  = threadIdx.x;
    int lane = tid & 63, wv = tid >> 6;
    int wr = wv >> 1, wc = wv & 1;
    int q = lane >> 4, m = lane & 15;
    int bx, by;
    if (TRI) {
        int t = (int)blockIdx.x;
        t = (t & 7) * 260 + (t >> 3);        // XCD swizzle: 2080 = 8*260 (bijective)
        by = (int)((sqrtf(8.0f * (float)t + 1.0f) - 1.0f) * 0.5f);
        while ((by + 1) * (by + 2) / 2 <= t) ++by;
        while (by * (by + 1) / 2 > t) --by;
        bx = t - by * (by + 1) / 2;          // bx <= by
    } else {
        bx = blockIdx.x; by = blockIdx.y;
    }
    int grow0 = row0 + by * 128;   // A rows (global)
    int gcol0 = bx * 128;          // B rows = C cols (global)
    f32x4 acc[4][4] = {};

    int lr = lane >> 3;   // row within 8-row group
    int lc = lane & 7;    // LDS chunk slot this lane fills
    for (int kc = 0; kc < 8; ++kc) {
        #pragma unroll
        for (int t = 0; t < 4; ++t) {
            int rb  = wv * 32 + t * 8;     // wave-uniform row base
            int r   = rb + lr;
            int fch = lc ^ (r & 7);        // XOR chunk swizzle (bank-conflict-free)
            async_ld16(xn + (size_t)(grow0 + r) * DIM + kc * 64 + fch * 8, &lA[rb * 64]);
            async_ld16(xn + (size_t)(gcol0 + r) * DIM + kc * 64 + fch * 8, &lB[rb * 64]);
        }
        __syncthreads();
        #pragma unroll
        for (int s = 0; s < 2; ++s) {
            bf16x8 af[4], bfr[4];
            #pragma unroll
            for (int i = 0; i < 4; ++i) {
                int ra = wr * 64 + i * 16 + m;
                af[i]  = *(const bf16x8*)&lA[ra * 64 + (((s * 4 + q) ^ (ra & 7)) * 8)];
                int rb2 = wc * 64 + i * 16 + m;
                bfr[i] = *(const bf16x8*)&lB[rb2 * 64 + (((s * 4 + q) ^ (rb2 & 7)) * 8)];
            }
            #pragma unroll
            for (int i = 0; i < 4; ++i)
                #pragma unroll
                for (int j = 0; j < 4; ++j)
                    acc[i][j] = __builtin_amdgcn_mfma_f32_16x16x32_bf16(af[i], bfr[j], acc[i][j], 0, 0, 0);
        }
        __syncthreads();
    }

    // ---- epilogue phase 1: stage row-tile in LDS + M digest ----
    // C/D layout: col=lane&15, row=quad*4+reg (m89/m91-verified)
    float cmf[4] = {-3.0f, -3.0f, -3.0f, -3.0f};     // per-j col maxima
    #pragma unroll
    for (int i = 0; i < 4; ++i) {
        float rmf[4] = {-3.0f, -3.0f, -3.0f, -3.0f}; // per-reg row maxima
        int rloc = wr * 64 + i * 16 + q * 4;         // local row base (0..127)
        #pragma unroll
        for (int j = 0; j < 4; ++j) {
            int cl = wc * 64 + j * 16 + m;           // local col
            int c  = gcol0 + cl;                     // global col
            #pragma unroll
            for (int reg = 0; reg < 4; ++reg) {
                int r    = rloc + reg;
                int grw  = row0 + by * 128 + r;
                float a  = acc[i][j][reg];
                bool dg  = (grw == c);
                float mv = dg ? -3.0f : a;
                rmf[reg] = fmaxf(rmf[reg], mv);
                cmf[j]   = fmaxf(cmf[j], mv);
                // dword-swizzled row-tile write (conflict-free; q=(r>>2)&3)
                int D = r * 64 + ((cl >> 1) ^ (q << 3));
                sh[D * 2 + (cl & 1)] = dg ? (ushort)0xC040 : f2bf(a);
            }
        }
        // row maxima: packed 2-rows/u32, reduce over 16 lanes (m) of each quad
        u32 p01 = mkey(rmf[0]) | (mkey(rmf[1]) << 16);
        u32 p23 = mkey(rmf[2]) | (mkey(rmf[3]) << 16);
        #pragma unroll
        for (int off = 1; off <= 8; off <<= 1) {
            p01 = pkmax(p01, (u32)__shfl_xor((int)p01, off));
            p23 = pkmax(p23, (u32)__shfl_xor((int)p23, off));
        }
        if (m == 0) {
            // transposed M: seg-major, rows rloc..rloc+3 contiguous -> one u64
            u64 pk = (u64)p01 | ((u64)p23 << 32);
            *(u64*)&M[(size_t)(bx * 2 + wc) * NROWS + (row0 + by * 128 + rloc)] = pk;
        }
    }
    if (TRI && bx != by) {
        // col maxima (mirror rows): packed 2-cols/u32, reduce over quads (q)
        u32 q01 = mkey(cmf[0]) | (mkey(cmf[1]) << 16);
        u32 q23 = mkey(cmf[2]) | (mkey(cmf[3]) << 16);
        q01 = pkmax(q01, (u32)__shfl_xor((int)q01, 16));
        q01 = pkmax(q01, (u32)__shfl_xor((int)q01, 32));
        q23 = pkmax(q23, (u32)__shfl_xor((int)q23, 16));
        q23 = pkmax(q23, (u32)__shfl_xor((int)q23, 32));
        if (q == 0) {
            // transposed M: 16 m-lanes write 16 contiguous ushorts per group
            int gc = gcol0 + wc * 64 + m;
            size_t sb = (size_t)(by * 2 + wr) * NROWS + gc;
            M[sb +  0] = (ushort)(q01 & 0xFFFFu);
            M[sb + 16] = (ushort)(q01 >> 16);
            M[sb + 32] = (ushort)(q23 & 0xFFFFu);
            M[sb + 48] = (ushort)(q23 >> 16);
        }
    }
    __syncthreads();

    // ---- epilogue phase 2a: coalesced row-major readback & store ----
    int tr = tid >> 4;       // 0..15
    int tc = tid & 15;       // 8-col chunk
    #pragma unroll
    for (int p = 0; p < 8; ++p) {
        int r  = p * 16 + tr;
        int qr = (r >> 2) & 3;
        uint4 v = *(const uint4*)&sh[(r * 64 + ((tc * 4) ^ (qr << 3))) * 2];
        *(uint4*)&C[(size_t)(by * 128 + r) * NROWS + gcol0 + tc * 8] = v;
    }

    if (TRI && bx != by) {
        // ---- phase 2b: re-stage transposed tile (packed row-pair b32) ----
        __syncthreads();
        u32* sh32 = (u32*)sh;
        #pragma unroll
        for (int i = 0; i < 4; ++i) {
            int cd0 = wr * 32 + i * 8 + q * 2;       // C^T dword col (rows rloc..+1)
            #pragma unroll
            for (int j = 0; j < 4; ++j) {
                int rT = wc * 64 + j * 16 + m;       // C^T row = orig col
                int gT = ((rT >> 2) & 3) << 3;
                u32 w0 = (u32)f2bf(acc[i][j][0]) | ((u32)f2bf(acc[i][j][1]) << 16);
                u32 w1 = (u32)f2bf(acc[i][j][2]) | ((u32)f2bf(acc[i][j][3]) << 16);
                sh32[rT * 64 + (cd0 ^ gT)]       = w0;
                sh32[rT * 64 + ((cd0 + 1) ^ gT)] = w1;
            }
        }
        __syncthreads();
        // ---- phase 2c: coalesced transposed readback & store ----
        #pragma unroll
        for (int p = 0; p < 8; ++p) {
            int ct = p * 16 + tr;                    // mirror global row gcol0+ct
            int gq = ((ct >> 2) & 3) << 3;
            uint4 v = *(const uint4*)&sh32[ct * 64 + ((tc * 4) ^ gq)];
            *(uint4*)&C[(size_t)(gcol0 + ct) * NROWS + by * 128 + tc * 8] = v;
        }
    }
}

// ---------------- select: ballot-bsearch top-20 + BCE ------------------------
__global__ __launch_bounds__(256) void k_select(const ushort* __restrict__ C,
                                                const ushort* __restrict__ M,
                                                const int* __restrict__ labels,
                                                int row0,
                                                float* __restrict__ partials) {
    __shared__ u32 s_surv[4][NSURV];
    __shared__ u32 s_seg[4][128];
    __shared__ u32 s_cnt[4];
    __shared__ u32 s_scnt[4];
    int lane = threadIdx.x & 63;
    int wv   = threadIdx.x >> 6;
    int prow = blockIdx.x * 4 + wv;
    int grow = row0 + prow;
    const ushort* rowC = C + (size_t)prow * NROWS;

    if (lane == 0) { s_cnt[wv] = 0; s_scnt[wv] = 0; }
    __syncthreads();

    // segment maxima (mono keys), transposed M: lane holds segs 2*lane, 2*lane+1
    u32 klo = (u32)M[(size_t)(2 * lane)     * NROWS + grow];
    u32 khi = (u32)M[(size_t)(2 * lane + 1) * NROWS + grow];

    // T = largest 16-bit value with count(seg_max >= T) >= KSEL
    u32 T = 0;
    #pragma unroll
    for (int b = 15; b >= 0; --b) {
        u32 cand = T | (1u << b);
        int c = __popcll(__ballot(klo >= cand)) + __popcll(__ballot(khi >= cand));
        if (c >= KSEL) T = cand;
    }

    // survivor-segment id list in LDS (replaces serial ctz chain)
    if (klo >= T) { u32 p = atomicAdd(&s_scnt[wv], 1u); s_seg[wv][p] = 2u * lane; }
    if (khi >= T) { u32 p = atomicAdd(&s_scnt[wv], 1u); s_seg[wv][p] = 2u * lane + 1u; }
    u32 nseg = s_scnt[wv];
    int grp = lane >> 3, sub = lane & 7;   // 8 lanes per segment

    // fast path: up to 32 segments as 4 independent uint4 loads (one mem epoch)
    int  sid[4];
    uint4 vv[4];
    #pragma unroll
    for (int t = 0; t < 4; ++t) {
        u32 ix = (u32)(t * 8 + grp);
        sid[t] = (ix < nseg) ? (int)s_seg[wv][ix] : -1;
    }
    #pragma unroll
    for (int t = 0; t < 4; ++t) {
        if (sid[t] >= 0) vv[t] = *(const uint4*)(rowC + sid[t] * 64 + sub * 8);
    }
    #pragma unroll
    for (int t = 0; t < 4; ++t) {
        if (sid[t] < 0) continue;
        u32 wds[4] = { vv[t].x, vv[t].y, vv[t].z, vv[t].w };
        u32 cbase = (u32)(sid[t] * 64 + sub * 8);
        #pragma unroll
        for (int h = 0; h < 4; ++h) {
            u32 w  = wds[h];
            u32 kA = mono16(w & 0xFFFFu);
            u32 kB = mono16(w >> 16);
            if (kA >= T) { u32 p = atomicAdd(&s_cnt[wv], 1u); if (p < NSURV) s_surv[wv][p] = (kA << 16) | (cbase + 2u * h); }
            if (kB >= T) { u32 p = atomicAdd(&s_cnt[wv], 1u); if (p < NSURV) s_surv[wv][p] = (kB << 16) | (cbase + 2u * h + 1u); }
        }
    }
    // rare tail: nseg > 32
    for (u32 base = 32; base < nseg; base += 8) {
        u32 ix = base + (u32)grp;
        if (ix >= nseg) continue;
        int s = (int)s_seg[wv][ix];
        uint4 v = *(const uint4*)(rowC + s * 64 + sub * 8);
        u32 wds[4] = { v.x, v.y, v.z, v.w };
        u32 cbase = (u32)(s * 64 + sub * 8);
        #pragma unroll
        for (int h = 0; h < 4; ++h) {
            u32 w  = wds[h];
            u32 kA = mono16(w & 0xFFFFu);
            u32 kB = mono16(w >> 16);
            if (kA >= T) { u32 p = atomicAdd(&s_cnt[wv], 1u); if (p < NSURV) s_surv[wv][p] = (kA << 16) | (cbase + 2u * h); }
            if (kB >= T) { u32 p = atomicAdd(&s_cnt[wv], 1u); if (p < NSURV) s_surv[wv][p] = (kB << 16) | (cbase + 2u * h + 1u); }
        }
    }

    u32 cnt = min(s_cnt[wv], (u32)NSURV);     // same-wave LDS: ordered
    int mylab = labels[grow];
    float loss = 0.0f;

    if (cnt <= 64u) {
        // fast path: one survivor per lane; V20 bsearch = 16 ballots
        u32 gg  = ((u32)lane < cnt) ? s_surv[wv][lane] : 0u;
        u32 key = gg >> 16;
        u32 V = 0;
        #pragma unroll
        for (int b = 15; b >= 0; --b) {
            u32 cand = V | (1u << b);
            if (__popcll(__ballot(key >= cand)) >= KSEL) V = cand;
        }
        int cgt  = __popcll(__ballot(key > V));
        int ceq  = __popcll(__ballot(gg != 0 && key == V));
        int need = KSEL - cgt;
        bool incl;
        if (ceq == need) {
            incl = (gg != 0) && (key >= V);
        } else {
            // more ties than slots: take `need` largest cols among ties
            u32 col = gg & 0xFFFFu;
            bool tie = (gg != 0) && (key == V);
            u32 Cv = 0;
            #pragma unroll
            for (int b = 15; b >= 0; --b) {
                u32 cand2 = Cv | (1u << b);
                if (__popcll(__ballot(tie && col >= cand2)) >= need) Cv = cand2;
            }
            incl = (key > V) || (tie && col >= Cv);   // cols unique -> exact
        }
        if (incl) {
            u32 col = gg & 0xFFFFu;
            u32 raw = (key & 0x8000u) ? (key ^ 0x8000u) : (key ^ 0xFFFFu);
            float v = __uint_as_float(raw << 16);
            float p = (v + 1.0f) * 0.5f;
            bool tm = (labels[col] == mylab);
            loss -= tm ? fmaxf(logf(p), -100.0f) : fmaxf(log1pf(-p), -100.0f);
        }
    } else {
        // fallback (rare): 8 survivors per lane
        u32 g[8];
        #pragma unroll
        for (int j = 0; j < 8; ++j) {
            u32 idx = (u32)lane + (u32)j * 64u;
            g[j] = (idx < cnt) ? s_surv[wv][idx] : 0u;
        }
        u32 V = 0;
        #pragma unroll
        for (int b = 15; b >= 0; --b) {
            u32 cand = V | (1u << b);
            int c = 0;
            #pragma unroll
            for (int j = 0; j < 8; ++j)
                c += __popcll(__ballot((g[j] >> 16) >= cand));
            if (c >= KSEL) V = cand;
        }
        int cgt = 0, ceq = 0;
        #pragma unroll
        for (int j = 0; j < 8; ++j) {
            cgt += __popcll(__ballot(g[j] != 0 && (g[j] >> 16) > V));
            ceq += __popcll(__ballot(g[j] != 0 && (g[j] >> 16) == V));
        }
        int need = KSEL - cgt;
        bool all_ties = (ceq == need);
        #pragma unroll
        for (int j = 0; j < 8; ++j) {
            u32 key = g[j] >> 16, col = g[j] & 0xFFFFu;
            if (g[j] != 0 && (key > V || (all_ties && key == V))) {
                u32 raw = (key & 0x8000u) ? (key ^ 0x8000u) : (key ^ 0xFFFFu);
                float v = __uint_as_float(raw << 16);
                float p = (v + 1.0f) * 0.5f;
                bool tm = (labels[col] == mylab);
                loss -= tm ? fmaxf(logf(p), -100.0f) : fmaxf(log1pf(-p), -100.0f);
            }
        }
        if (!all_ties) {
            for (int r = 0; r < need; ++r) {
                u32 best = 0;
                #pragma unroll
                for (int j = 0; j < 8; ++j) {
                    u32 c2 = (g[j] != 0 && (g[j] >> 16) == V) ? ((g[j] & 0xFFFFu) + 1u) : 0u;
                    best = max(best, c2);
                }
                #pragma unroll
                for (int off = 32; off; off >>= 1) best = max(best, (u32)__shfl_xor((int)best, off));
                #pragma unroll
                for (int j = 0; j < 8; ++j) {
                    if (g[j] != 0 && (g[j] >> 16) == V && ((g[j] & 0xFFFFu) + 1u) == best) {
                        u32 col = g[j] & 0xFFFFu;
                        u32 raw = (V & 0x8000u) ? (V ^ 0x8000u) : (V ^ 0xFFFFu);
                        float v = __uint_as_float(raw << 16);
                        float p = (v + 1.0f) * 0.5f;
                        bool tm = (labels[col] == mylab);
                        loss -= tm ? fmaxf(logf(p), -100.0f) : fmaxf(log1pf(-p), -100.0f);
                        g[j] = 0;
                    }
                }
            }
        }
    }

    #pragma unroll
    for (int off = 32; off; off >>= 1) loss += __shfl_xor(loss, off);
    if (lane == 0) partials[grow] = loss;
}

__global__ __launch_bounds__(256) void k_final(const float* __restrict__ partials,
                                               float* __restrict__ out) {
    __shared__ float s[4];
    int tid = threadIdx.x, lane = tid & 63, wvi = tid >> 6;
    const float4* p4 = (const float4*)partials;
    float sum = 0.0f;
    #pragma unroll
    for (int i = 0; i < 8; ++i) {
        float4 v = p4[tid + i * 256];
        sum += v.x + v.y + v.z + v.w;
    }
    #pragma unroll
    for (int off = 32; off; off >>= 1) sum += __shfl_xor(sum, off);
    if (lane == 0) s[wvi] = sum;
    __syncthreads();
    if (tid == 0) out[0] = (s[0] + s[1] + s[2] + s[3]) * (1.0f / (float)(NROWS * KSEL));
}

extern "C" void kernel_launch(void* const* d_in, const int* in_sizes, int n_in,
                              void* d_out, int out_size, void* d_ws, size_t ws_size,
                              hipStream_t stream) {
    const float* batch  = (const float*)d_in[0];
    const int*   labels = (const int*)d_in[1];

    ushort* xn = (ushort*)d_ws;
    ushort* C  = xn + (size_t)NROWS * DIM;
    // M (2 MB, transposed seg-major) and partials (32 KB) live in the batch
    // input buffer (16 MB): batch is fully consumed by k_norm first.
    ushort* M        = (ushort*)d_in[0];
    float*  partials = (float*)((char*)d_in[0] + (4u << 20));

    size_t need_full = (size_t)NROWS * DIM * 2 + (size_t)NROWS * NROWS * 2;

    k_norm<<<NROWS / 4, 256, 0, stream>>>(batch, xn);

    if (ws_size >= need_full) {
        // full symmetric path: 2080 lower-triangle blocks, one select pass
        k_gemm<true><<<dim3(64 * 65 / 2), 256, 0, stream>>>(xn, C, M, 0);
        k_select<<<NROWS / 4, 256, 0, stream>>>(C, M, labels, 0, partials);
    } else {
        // fallback: panel path (24 MB of ws)
        for (int p = 0; p < NROWS / PANEL; ++p) {
            k_gemm<false><<<dim3(64, PANEL / 128), 256, 0, stream>>>(xn, C, M, p * PANEL);
            k_select<<<PANEL / 4, 256, 0, stream>>>(C, M, labels, p * PANEL, partials);
        }
    }
    k_final<<<1, 256, 0, stream>>>(partials, (float*)d_out);
}